// Round 6
// baseline (937.910 us; speedup 1.0000x reference)
//
#include <hip/hip_runtime.h>
#include <stdint.h>

// Net_18021682774696 — MTGNN-ish: 3x { TCN(2 gated) ; skip ; 3x mixprop ; LN+ReLU } + end convs.
// Round 6: launch-count reduction (38 -> 22), fused ktcnfuse/kfinal, combine as clean
// LDS-free GEMM over pbufT (v-major features), stats folded into combine, rcp folded
// into prop epilogue, kcvtT bank-conflict fix (u32 row-pair packing, stride 34).

typedef uint16_t u16;
typedef uint32_t u32;
typedef __attribute__((ext_vector_type(8))) short s8v;
typedef __attribute__((ext_vector_type(4))) float f4v;

#define MFMA16(a,b,c) __builtin_amdgcn_mfma_f32_16x16x32_bf16(a,b,c,0,0,0)

constexpr long PB  = 262144;  // pbuf batch stride (4 slots x 32ch x 2048)
constexpr long SL  = 65536;   // pbuf slot stride
constexpr long TB  = 393216;  // pbufT batch stride (2048 x 192)
constexpr long DYB = 4194304;

__device__ __forceinline__ float b2f(u16 u){ union{u32 i; float f;} x; x.i=(u32)u<<16; return x.f; }
__device__ __forceinline__ u16 f2b(float f){
  u32 u = __builtin_bit_cast(u32, f);
  u32 r = (u + 0x7fffu + ((u >> 16) & 1u)) >> 16;   // RNE
  return (u16)r;
}

// ---------------------------------------------------------------------------
__global__ __launch_bounds__(256) void kdetect(const u16* __restrict__ x, int* __restrict__ flag)
{
  const int i = threadIdx.x;
  const uint4* p = (const uint4*)x;
  int cnt = 0;
  #pragma unroll
  for (int q = 0; q < 32; q++) {
    const uint4 v = p[i + q*256];
    const u32 w[4] = {v.x, v.y, v.z, v.w};
    #pragma unroll
    for (int e = 0; e < 4; e++) {
      if ((w[e] & 0x7F80u) == 0x7F80u) cnt++;
      if (((w[e] >> 16) & 0x7F80u) == 0x7F80u) cnt++;
    }
  }
  __shared__ int s[256];
  s[i] = cnt; __syncthreads();
  for (int st = 128; st; st >>= 1) { if (i < st) s[i] += s[i+st]; __syncthreads(); }
  if (i == 0) flag[0] = (s[0] > 0) ? 1 : 0;
}

struct CvtTab { const void* s[18]; u16* d[18]; int n4[18]; };
__global__ __launch_bounds__(256) void kcvt_small(CvtTab tb, const int* __restrict__ flag)
{
  const int e = blockIdx.y;
  const int i = blockIdx.x*256 + threadIdx.x;
  if (i >= tb.n4[e]) return;
  if (*flag) {
    const float4 v = ((const float4*)tb.s[e])[i];
    u16 o[4]; o[0]=f2b(v.x); o[1]=f2b(v.y); o[2]=f2b(v.z); o[3]=f2b(v.w);
    *(uint2*)(tb.d[e] + (long)i*4) = *(uint2*)o;
  } else {
    *(uint2*)(tb.d[e] + (long)i*4) = ((const uint2*)tb.s[e])[i];
  }
}

// ---------------------------------------------------------------------------
// kstg: static graph convert (+ raw rowsums, one wave per row, no atomics).
// ---------------------------------------------------------------------------
__global__ __launch_bounds__(256) void kstg(
    const void* __restrict__ src, u16* __restrict__ dst, float* __restrict__ rst,
    const int* __restrict__ flag)
{
  const int wave = threadIdx.x>>6, lane = threadIdx.x&63;
  const int row = blockIdx.x*4 + wave;
  const int fl = *flag;
  float s = 0.f;
  #pragma unroll
  for (int q = 0; q < 8; q++) {
    const long off = (long)row*2048 + q*256 + lane*4;
    u16 v4[4];
    if (fl) {
      const float4 f = *(const float4*)((const float*)src + off);
      v4[0]=f2b(f.x); v4[1]=f2b(f.y); v4[2]=f2b(f.z); v4[3]=f2b(f.w);
    } else {
      *(uint2*)v4 = *(const uint2*)((const u16*)src + off);
    }
    *(uint2*)(dst + off) = *(uint2*)v4;
    #pragma unroll
    for (int e = 0; e < 4; e++) s += b2f(v4[e]);
  }
  #pragma unroll
  for (int off = 32; off; off >>= 1) s += __shfl_down(s, off, 64);
  if (lane == 0) rst[row] = s;   // raw sum; epilogues do 1/(1+s)
}

// ---------------------------------------------------------------------------
// kcvtT: dy -> dyb + dytb + raw row/col sums. 64x256 tile.
//   LDS: u32 row-pair packing, stride 34 -> 2-way conflicts only (free).
// ---------------------------------------------------------------------------
__global__ __launch_bounds__(256) void kcvtT(
    const void* __restrict__ src, u16* __restrict__ dyb, u16* __restrict__ dytb,
    float* __restrict__ rsum, float* __restrict__ csum, const int* __restrict__ flag)
{
  __shared__ u32 tt[256][34];
  const int tid = threadIdx.x;
  const int b = blockIdx.z;
  const long r0 = (long)blockIdx.y*64, c0 = (long)blockIdx.x*256;
  const int rp = tid>>3, c4 = (tid&7)*4;
  const long base = (long)b*4194304;
  const int fl = *flag;
  float rs0 = 0.f, rs1 = 0.f;
  #pragma unroll
  for (int j = 0; j < 8; j++) {
    const long cc = c0 + c4 + 32*j;
    u16 v0_[4], v1_[4];
    if (fl) {
      const float* s0 = (const float*)src + base + (r0 + 2*rp)*2048 + cc;
      const float4 f0 = *(const float4*)s0;
      const float4 f1 = *(const float4*)(s0 + 2048);
      v0_[0]=f2b(f0.x); v0_[1]=f2b(f0.y); v0_[2]=f2b(f0.z); v0_[3]=f2b(f0.w);
      v1_[0]=f2b(f1.x); v1_[1]=f2b(f1.y); v1_[2]=f2b(f1.z); v1_[3]=f2b(f1.w);
    } else {
      const u16* s0 = (const u16*)src + base + (r0 + 2*rp)*2048 + cc;
      *(uint2*)v0_ = *(const uint2*)s0;
      *(uint2*)v1_ = *(const uint2*)(s0 + 2048);
    }
    *(uint2*)(dyb + base + (r0+2*rp)*2048 + cc)   = *(uint2*)v0_;
    *(uint2*)(dyb + base + (r0+2*rp+1)*2048 + cc) = *(uint2*)v1_;
    #pragma unroll
    for (int e = 0; e < 4; e++) {
      rs0 += b2f(v0_[e]); rs1 += b2f(v1_[e]);
      tt[c4 + 32*j + e][rp] = (u32)v0_[e] | ((u32)v1_[e] << 16);
    }
  }
  rs0 += __shfl_down(rs0, 4, 8); rs0 += __shfl_down(rs0, 2, 8); rs0 += __shfl_down(rs0, 1, 8);
  rs1 += __shfl_down(rs1, 4, 8); rs1 += __shfl_down(rs1, 2, 8); rs1 += __shfl_down(rs1, 1, 8);
  if ((tid & 7) == 0) {
    atomicAdd(rsum + b*2048 + r0 + 2*rp, rs0);
    atomicAdd(rsum + b*2048 + r0 + 2*rp + 1, rs1);
  }
  __syncthreads();
  u32 cw[32];
  #pragma unroll
  for (int q = 0; q < 16; q++) {
    const uint2 w2 = *(const uint2*)&tt[tid][q*2];
    cw[q*2] = w2.x; cw[q*2+1] = w2.y;
  }
  u16 col[64]; float cs = 0.f;
  #pragma unroll
  for (int rr = 0; rr < 32; rr++) {
    col[2*rr]   = (u16)(cw[rr] & 0xffffu);
    col[2*rr+1] = (u16)(cw[rr] >> 16);
    cs += b2f(col[2*rr]) + b2f(col[2*rr+1]);
  }
  u16* dp = dytb + base + (c0 + tid)*2048 + r0;
  #pragma unroll
  for (int q = 0; q < 8; q++) *(uint4*)(dp + q*8) = *(uint4*)&col[q*8];
  atomicAdd(csum + b*2048 + c0 + tid, cs);
}

// ---------------------------------------------------------------------------
// kprop3: fused 3-graph propagation hop, register double-buffered pipeline.
//   out_g[v,c] = (sum_k A_g[v,k] X_g[c,k] + X_g[c,v]) / (1 + rawsum_g[v])
//   WRP: also write channel-first pbuf slot (needed for hop2's X). Always
//   writes pbufT (v-major, for combine GEMM).
// ---------------------------------------------------------------------------
struct P3 {
  const u16 *A0, *A1, *A2; long ab0, ab1, ab2;
  const u16 *X0, *X1, *X2;
  const float *R0, *R1, *R2; long rb0, rb1, rb2;
  u16 *O0, *O1, *O2;   // pbuf slots (WRP only)
  u16 *T0, *T1, *T2;   // pbufT + column offset
};

template<int SHAREX, int WRP>
__global__ __launch_bounds__(256) void kprop3(P3 p, long x_bs, long o_bs)
{
  constexpr int NS = SHAREX ? 5 : 9;
  __shared__ f4v red[4][6][64];
  const int tid = threadIdx.x, wave = tid>>6, lane = tid&63;
  const int lw = lane&15, quad = lane>>4;
  const int v0 = blockIdx.x*16;
  const int b = blockIdx.y;
  const long ko = (long)(wave*512 + quad*8);
  const u16* ptr[9];
  ptr[0] = p.A0 + (long)b*p.ab0 + (long)(v0+lw)*2048 + ko;
  ptr[1] = p.A1 + (long)b*p.ab1 + (long)(v0+lw)*2048 + ko;
  ptr[2] = p.A2 + (long)b*p.ab2 + (long)(v0+lw)*2048 + ko;
  ptr[3] = p.X0 + (long)b*x_bs + (long)lw*2048 + ko;
  ptr[4] = p.X0 + (long)b*x_bs + (long)(16+lw)*2048 + ko;
  if (!SHAREX) {
    ptr[5] = p.X1 + (long)b*x_bs + (long)lw*2048 + ko;
    ptr[6] = p.X1 + (long)b*x_bs + (long)(16+lw)*2048 + ko;
    ptr[7] = p.X2 + (long)b*x_bs + (long)lw*2048 + ko;
    ptr[8] = p.X2 + (long)b*x_bs + (long)(16+lw)*2048 + ko;
  }
  f4v acc[6];
  #pragma unroll
  for (int t = 0; t < 6; t++) acc[t] = (f4v){0.f,0.f,0.f,0.f};
  s8v B0[NS][2], B1[NS][2];

  auto LD = [&](s8v (&B)[NS][2], int off){
    #pragma unroll
    for (int s = 0; s < NS; s++) {
      B[s][0] = *(const s8v*)(ptr[s] + off);
      B[s][1] = *(const s8v*)(ptr[s] + off + 32);
    }
  };
  auto FM = [&](s8v (&B)[NS][2]){
    #pragma unroll
    for (int u = 0; u < 2; u++) {
      if (SHAREX) {
        acc[0] = MFMA16(B[0][u], B[3][u], acc[0]);
        acc[1] = MFMA16(B[0][u], B[4][u], acc[1]);
        acc[2] = MFMA16(B[1][u], B[3][u], acc[2]);
        acc[3] = MFMA16(B[1][u], B[4][u], acc[3]);
        acc[4] = MFMA16(B[2][u], B[3][u], acc[4]);
        acc[5] = MFMA16(B[2][u], B[4][u], acc[5]);
      } else {
        acc[0] = MFMA16(B[0][u], B[3][u], acc[0]);
        acc[1] = MFMA16(B[0][u], B[4][u], acc[1]);
        acc[2] = MFMA16(B[1][u], B[5][u], acc[2]);
        acc[3] = MFMA16(B[1][u], B[6][u], acc[3]);
        acc[4] = MFMA16(B[2][u], B[7][u], acc[4]);
        acc[5] = MFMA16(B[2][u], B[8][u], acc[5]);
      }
    }
  };

  LD(B0, 0);
  #pragma unroll 1
  for (int i = 0; i < 3; i++) {
    LD(B1, 64);
    FM(B0);
    LD(B0, 128);
    FM(B1);
    #pragma unroll
    for (int s = 0; s < NS; s++) ptr[s] += 128;
  }
  LD(B1, 64);
  FM(B0);
  FM(B1);

  #pragma unroll
  for (int t = 0; t < 6; t++) red[wave][t][lane] = acc[t];
  __syncthreads();
  if (wave < 3) {
    const int vb = v0 + quad*4;
    const u16* Xg   = (wave==0) ? p.X0 : (wave==1) ? (SHAREX ? p.X0 : p.X1) : (SHAREX ? p.X0 : p.X2);
    const float* Rg = (wave==0) ? p.R0 : (wave==1) ? p.R1 : p.R2;
    const long rbs  = (wave==0) ? p.rb0 : (wave==1) ? p.rb1 : p.rb2;
    u16* Og         = (wave==0) ? p.O0 : (wave==1) ? p.O1 : p.O2;
    u16* Tg         = (wave==0) ? p.T0 : (wave==1) ? p.T1 : p.T2;
    const float4 rv = *(const float4*)(Rg + (long)b*rbs + vb);
    float ri[4];
    #pragma unroll
    for (int r = 0; r < 4; r++) ri[r] = 1.f/(1.f + (&rv.x)[r]);
    #pragma unroll
    for (int nt = 0; nt < 2; nt++) {
      const int t = wave*2 + nt;
      f4v s = red[0][t][lane] + red[1][t][lane] + red[2][t][lane] + red[3][t][lane];
      const int c = nt*16 + lw;
      const u16* dp = Xg + (long)b*x_bs + (long)c*2048 + vb;
      u16 pk[4];
      #pragma unroll
      for (int r = 0; r < 4; r++) pk[r] = f2b((s[r] + b2f(dp[r])) * ri[r]);
      if (WRP) *(uint2*)(Og + (long)b*o_bs + (long)c*2048 + vb) = *(uint2*)pk;
      u16* tp = Tg + (long)b*TB + (long)vb*192 + c;
      #pragma unroll
      for (int r = 0; r < 4; r++) tp[r*192] = pk[r];
    }
  }
}

// ---------------------------------------------------------------------------
// ktcnfuse: tcn1 -> tcn2 -> skip for a 64-row block (LDS intermediates).
// ---------------------------------------------------------------------------
__global__ __launch_bounds__(256) void ktcnfuse(
    const u16* __restrict__ hid,
    const u16* __restrict__ Wf1, const u16* __restrict__ bf1,
    const u16* __restrict__ Wg1, const u16* __restrict__ bg1,
    const u16* __restrict__ Wf2, const u16* __restrict__ bf2,
    const u16* __restrict__ Wg2, const u16* __restrict__ bg2,
    const u16* __restrict__ sW, const u16* __restrict__ sb,
    float* __restrict__ skipbuf, int addprev)
{
  __shared__ u16 h1[64][136];
  __shared__ u16 h2[64][136];
  const int tid = threadIdx.x, wave = tid>>6, lane = tid&63, lw = lane&15, quad = lane>>4;
  const long j0 = (long)blockIdx.x*64;
  const f4v zero = {0.f,0.f,0.f,0.f};

  // ---- tcn1 (A from global hid) ----
  {
    f4v af[8], ag[8];
    #pragma unroll
    for (int nt=0; nt<8; nt++){ af[nt]=zero; ag[nt]=zero; }
    const u16* Arow = hid + (j0 + wave*16 + lw)*128 + quad*8;
    #pragma unroll
    for (int k0 = 0; k0 < 128; k0 += 32) {
      s8v a = *(const s8v*)(Arow + k0);
      #pragma unroll
      for (int nt = 0; nt < 8; nt++) {
        const int o = nt*16 + lw;
        af[nt] = MFMA16(a, *(const s8v*)(Wf1 + o*128 + k0 + quad*8), af[nt]);
        ag[nt] = MFMA16(a, *(const s8v*)(Wg1 + o*128 + k0 + quad*8), ag[nt]);
      }
    }
    #pragma unroll
    for (int nt = 0; nt < 8; nt++) {
      const int o = nt*16 + lw;
      const float fb = b2f(bf1[o]), gb = b2f(bg1[o]);
      #pragma unroll
      for (int rr = 0; rr < 4; rr++) {
        const int row = wave*16 + quad*4 + rr;
        const float f = af[nt][rr] + fb, g = ag[nt][rr] + gb;
        const float e2 = __expf(2.f*f);
        const float th = 1.f - 2.f/(e2 + 1.f);
        const float sg = 1.f/(1.f + __expf(-g));
        h1[row][o] = f2b(th*sg);
      }
    }
  }
  __syncthreads();
  // ---- tcn2 (A from LDS h1) ----
  {
    f4v af[8], ag[8];
    #pragma unroll
    for (int nt=0; nt<8; nt++){ af[nt]=zero; ag[nt]=zero; }
    #pragma unroll
    for (int k0 = 0; k0 < 128; k0 += 32) {
      s8v a = *(const s8v*)&h1[wave*16 + lw][k0 + quad*8];
      #pragma unroll
      for (int nt = 0; nt < 8; nt++) {
        const int o = nt*16 + lw;
        af[nt] = MFMA16(a, *(const s8v*)(Wf2 + o*128 + k0 + quad*8), af[nt]);
        ag[nt] = MFMA16(a, *(const s8v*)(Wg2 + o*128 + k0 + quad*8), ag[nt]);
      }
    }
    #pragma unroll
    for (int nt = 0; nt < 8; nt++) {
      const int o = nt*16 + lw;
      const float fb = b2f(bf2[o]), gb = b2f(bg2[o]);
      #pragma unroll
      for (int rr = 0; rr < 4; rr++) {
        const int row = wave*16 + quad*4 + rr;
        const float f = af[nt][rr] + fb, g = ag[nt][rr] + gb;
        const float e2 = __expf(2.f*f);
        const float th = 1.f - 2.f/(e2 + 1.f);
        const float sg = 1.f/(1.f + __expf(-g));
        h2[row][o] = f2b(th*sg);
      }
    }
  }
  __syncthreads();
  // ---- skip (A from LDS h2, N=256, f32 accumulate buffer) ----
  {
    f4v acc[16];
    #pragma unroll
    for (int nt=0; nt<16; nt++) acc[nt] = zero;
    #pragma unroll
    for (int k0 = 0; k0 < 128; k0 += 32) {
      s8v a = *(const s8v*)&h2[wave*16 + lw][k0 + quad*8];
      #pragma unroll
      for (int nt = 0; nt < 16; nt++) {
        const int o = nt*16 + lw;
        acc[nt] = MFMA16(a, *(const s8v*)(sW + o*128 + k0 + quad*8), acc[nt]);
      }
    }
    #pragma unroll
    for (int nt = 0; nt < 16; nt++) {
      const int o = nt*16 + lw;
      const float bv = b2f(sb[o]);
      #pragma unroll
      for (int rr = 0; rr < 4; rr++) {
        const long j = j0 + wave*16 + quad*4 + rr;
        float v = acc[nt][rr] + bv;
        if (addprev) v += skipbuf[j*256 + o];
        skipbuf[j*256 + o] = v;
      }
    }
  }
}

// ---------------------------------------------------------------------------
// kcomb: xpre = Weff @ [x | p-features] + bias + residual; + LN stats atomics.
//   A: k<32 from hid rows (x), k>=32 from pbufT rows. K=224, N=32.
// ---------------------------------------------------------------------------
__global__ __launch_bounds__(256) void kcomb(
    const u16* __restrict__ hid, const u16* __restrict__ pT,
    const u16* __restrict__ slot0, const u16* __restrict__ weff,
    const float* __restrict__ bw, float* __restrict__ xpre, float* __restrict__ rawp)
{
  const int tid = threadIdx.x, wave = tid>>6, lane = tid&63, lw = lane&15, quad = lane>>4;
  const long j0 = (long)blockIdx.x*64;
  const int b = (int)(j0 >> 11);
  f4v acc[2] = {{0.f,0.f,0.f,0.f},{0.f,0.f,0.f,0.f}};
  const u16* Ah = hid + (j0 + wave*16 + lw)*128 + quad*8;
  const u16* At = pT + (j0 + wave*16 + lw)*192 + quad*8;
  #pragma unroll
  for (int cc = 0; cc < 7; cc++) {
    s8v a = (cc == 0) ? *(const s8v*)Ah : *(const s8v*)(At + (cc-1)*32);
    #pragma unroll
    for (int nt = 0; nt < 2; nt++) {
      s8v w = *(const s8v*)(weff + (nt*16+lw)*224 + cc*32 + quad*8);
      acc[nt] = MFMA16(a, w, acc[nt]);
    }
  }
  float s = 0.f, q = 0.f;
  const int vbase = (int)(j0 & 2047) + wave*16 + quad*4;
  #pragma unroll
  for (int nt = 0; nt < 2; nt++) {
    const int c = nt*16 + lw;
    const float bb = bw[c];
    u16 r4[4];
    *(uint2*)r4 = *(const uint2*)(slot0 + (long)b*PB + (long)c*2048 + vbase);
    float4 st;
    #pragma unroll
    for (int r = 0; r < 4; r++) {
      const float val = acc[nt][r] + bb + b2f(r4[r]);
      (&st.x)[r] = val; s += val; q += val*val;
    }
    *(float4*)(xpre + (long)b*65536 + (long)c*2048 + vbase) = st;
  }
  __shared__ float ss[256], qq[256];
  ss[tid] = s; qq[tid] = q;
  __syncthreads();
  for (int st = 128; st; st >>= 1) {
    if (tid < st) { ss[tid] += ss[tid+st]; qq[tid] += qq[tid+st]; }
    __syncthreads();
  }
  if (tid == 0) { atomicAdd(rawp + b*2, ss[0]); atomicAdd(rawp + b*2 + 1, qq[0]); }
}

// ---------------------------------------------------------------------------
// kapply: x = relu(LN(xpre)*w+b) -> slot0 (cf bf16) + hid cols 0..31 (cl bf16)
// ---------------------------------------------------------------------------
__global__ __launch_bounds__(256) void kapply(
    const float* __restrict__ xpre, const float* __restrict__ raw,
    const u16* __restrict__ nw, const u16* __restrict__ nb,
    u16* __restrict__ slot0, u16* __restrict__ hid)
{
  __shared__ u16 t[32][72];
  const int tid = threadIdx.x, b = blockIdx.y, v0 = blockIdx.x*64;
  const float mu = raw[b*2] * (1.f/65536.f);
  const float var = raw[b*2+1] * (1.f/65536.f) - mu*mu;
  const float rs = rsqrtf(var + 1e-5f);
  const int c = tid>>3, v8 = (tid&7)*8;
  const long boff = (long)c*2048 + v0 + v8;
  float4 xa = *(const float4*)(xpre + (long)b*65536 + boff);
  float4 xbv = *(const float4*)(xpre + (long)b*65536 + boff + 4);
  u16 wv[8], bv[8], o8[8];
  *(uint4*)wv = *(const uint4*)(nw + boff);
  *(uint4*)bv = *(const uint4*)(nb + boff);
  const float xs[8] = {xa.x, xa.y, xa.z, xa.w, xbv.x, xbv.y, xbv.z, xbv.w};
  #pragma unroll
  for (int e = 0; e < 8; e++) {
    float y = (xs[e] - mu) * rs * b2f(wv[e]) + b2f(bv[e]);
    y = fmaxf(y, 0.f);
    o8[e] = f2b(y);
    t[c][v8 + e] = o8[e];
  }
  *(uint4*)(slot0 + (long)b*PB + boff) = *(uint4*)o8;
  __syncthreads();
  const int jl = tid>>2, c8 = (tid&3)*8;
  u16 q8[8];
  #pragma unroll
  for (int e = 0; e < 8; e++) q8[e] = t[c8 + e][jl];
  *(uint4*)(hid + ((long)b*2048 + v0 + jl)*128 + c8) = *(uint4*)q8;
}

// ---------------------------------------------------------------------------
// khid0: convert+transpose {x,spat,tde,twe} -> hid; x -> pbuf slot0.
// ---------------------------------------------------------------------------
__global__ __launch_bounds__(256) void khid0(
    const void* __restrict__ x, const void* __restrict__ spat,
    const void* __restrict__ tde, const void* __restrict__ twe,
    u16* __restrict__ hid, u16* __restrict__ slot0, const int* __restrict__ flag)
{
  __shared__ u16 t[32][72];
  const int tid = threadIdx.x, b = blockIdx.y, v0 = blockIdx.x*64;
  const int fl = *flag;
  const void* srcs[4] = {x, spat, tde, twe};
  #pragma unroll
  for (int e = 0; e < 4; e++) {
    const int c = tid>>3, v8 = (tid&7)*8;
    const long boff = (long)c*2048 + v0 + v8;
    u16 o8[8];
    if (fl) {
      const float* sp = (const float*)srcs[e] + (long)b*65536 + boff;
      const float4 a = ((const float4*)sp)[0], bb = ((const float4*)sp)[1];
      o8[0]=f2b(a.x); o8[1]=f2b(a.y); o8[2]=f2b(a.z); o8[3]=f2b(a.w);
      o8[4]=f2b(bb.x); o8[5]=f2b(bb.y); o8[6]=f2b(bb.z); o8[7]=f2b(bb.w);
    } else {
      *(uint4*)o8 = *(const uint4*)((const u16*)srcs[e] + (long)b*65536 + boff);
    }
    if (e == 0) *(uint4*)(slot0 + (long)b*PB + boff) = *(uint4*)o8;
    *(uint4*)&t[c][v8] = *(uint4*)o8;
    __syncthreads();
    const int jl = tid>>2, c8 = (tid&3)*8;
    u16 q8[8];
    #pragma unroll
    for (int i = 0; i < 8; i++) q8[i] = t[c8 + i][jl];
    *(uint4*)(hid + ((long)b*2048 + v0 + jl)*128 + e*32 + c8) = *(uint4*)q8;
    __syncthreads();
  }
}

// ---------------------------------------------------------------------------
// kweff3: fold mixprop MLPs into Weff for all 3 layers.
// ---------------------------------------------------------------------------
__global__ __launch_bounds__(256) void kweff3(
    const u16* __restrict__ g0W, const u16* __restrict__ g1W, const u16* __restrict__ g2W,
    const u16* __restrict__ g0b, const u16* __restrict__ g1b, const u16* __restrict__ g2b,
    u16* __restrict__ weff, float* __restrict__ bw)
{
  const int layer = blockIdx.y;
  const int ioff = layer*3072, boff = layer*32;
  u16* wout = weff + layer*7168;
  float* bout = bw + layer*32;
  const int idx = blockIdx.x*256 + threadIdx.x;
  if (idx < 32) bout[idx] = b2f(g0b[boff+idx]) + b2f(g1b[boff+idx]) + b2f(g2b[boff+idx]);
  if (idx >= 7168) return;
  const int o = idx / 224, m = idx % 224;
  const u16* Ws[3] = {g0W + ioff, g1W + ioff, g2W + ioff};
  float val;
  if (m < 32) {
    val = 0.f;
    #pragma unroll
    for (int g = 0; g < 3; g++) {
      const float w0 = b2f(Ws[g][o*96 + m]);
      const float w1 = b2f(Ws[g][o*96 + 32 + m]);
      const float w2 = b2f(Ws[g][o*96 + 64 + m]);
      val += w0 + 0.05f*(w1 + w2);
    }
  } else {
    const int f = (m - 32) >> 5, cc = m & 31;
    const int g = f >> 1, typ = f & 1;
    const float w1 = b2f(Ws[g][o*96 + 32 + cc]);
    const float w2 = b2f(Ws[g][o*96 + 64 + cc]);
    val = (typ == 0) ? (0.95f*w1 + 0.0475f*w2) : (0.9025f*w2);
  }
  wout[o*224 + m] = f2b(val);
}

// ---------------------------------------------------------------------------
// kfinal: skip += skipE(x); out = end(skip). Fused (LDS intermediate).
// ---------------------------------------------------------------------------
__global__ __launch_bounds__(256) void kfinal(
    const u16* __restrict__ hid, const u16* __restrict__ sEW, const u16* __restrict__ sEb,
    const float* __restrict__ skipbuf, const u16* __restrict__ eW, const u16* __restrict__ eb,
    void* __restrict__ outv, const int* __restrict__ flag)
{
  __shared__ u16 xs[64][264];
  const int tid = threadIdx.x, wave = tid>>6, lane = tid&63, lw = lane&15, quad = lane>>4;
  const long j0 = (long)blockIdx.x*64;
  const f4v zero = {0.f,0.f,0.f,0.f};
  // skipE: K=32 (x lives in hid cols 0..31)
  {
    f4v acc[16];
    #pragma unroll
    for (int nt=0; nt<16; nt++) acc[nt] = zero;
    s8v a = *(const s8v*)(hid + (j0 + wave*16 + lw)*128 + quad*8);
    #pragma unroll
    for (int nt = 0; nt < 16; nt++) {
      const int o = nt*16 + lw;
      acc[nt] = MFMA16(a, *(const s8v*)(sEW + o*32 + quad*8), acc[nt]);
    }
    #pragma unroll
    for (int nt = 0; nt < 16; nt++) {
      const int o = nt*16 + lw;
      const float bv = b2f(sEb[o]);
      #pragma unroll
      for (int rr = 0; rr < 4; rr++) {
        const int row = wave*16 + quad*4 + rr;
        const long j = j0 + row;
        xs[row][o] = f2b(acc[nt][rr] + bv + skipbuf[j*256 + o]);
      }
    }
  }
  __syncthreads();
  // end: K=256, N=12
  {
    f4v acc = zero;
    #pragma unroll
    for (int k0 = 0; k0 < 256; k0 += 32) {
      s8v a = *(const s8v*)&xs[wave*16 + lw][k0 + quad*8];
      s8v b = {0,0,0,0,0,0,0,0};
      if (lw < 12) b = *(const s8v*)(eW + lw*256 + k0 + quad*8);
      acc = MFMA16(a, b, acc);
    }
    if (lw < 12) {
      const float bv = b2f(eb[lw]);
      const int fl = *flag;
      #pragma unroll
      for (int rr = 0; rr < 4; rr++) {
        const long j = j0 + wave*16 + quad*4 + rr;
        const long oi = (j >> 11)*24576 + lw*2048 + (j & 2047);
        const float val = acc[rr] + bv;
        if (fl) ((float*)outv)[oi] = val;
        else    ((u16*)outv)[oi]   = f2b(val);
      }
    }
  }
}

// ---------------------------------------------------------------------------
extern "C" void kernel_launch(void* const* d_in, const int* in_sizes, int n_in,
                              void* d_out, int out_size, void* d_ws, size_t ws_size,
                              hipStream_t stream)
{
  (void)in_sizes; (void)n_in; (void)out_size; (void)ws_size;

  char* ws = (char*)d_ws;
  u16*   pbuf  = (u16*)(ws + 0);          // [8][4*32][2048] bf16 (x, p1g0, p1g1, p1g2)
  u16*   pbufT = (u16*)(ws + 4194304);    // [8][2048][192] bf16 (v-major features)
  u16*   hid   = (u16*)(ws + 10485760);   // [16384][128] bf16
  float* skip  = (float*)(ws + 14680064); // [16384][256] f32
  float* xpre  = (float*)(ws + 31457280); // [8][32][2048] f32
  u16*   weff  = (u16*)(ws + 33554432);   // [3][32][224]
  float* bw    = (float*)(ws + 33597440); // [3][32]
  float* rst   = (float*)(ws + 33598464); // [2048] raw static rowsums
  float* rdy   = (float*)(ws + 33606656); // [8][2048] raw dy rowsums (memset region start)
  float* cdy   = (float*)(ws + 33672192); // [8][2048] raw dy colsums
  float* raw   = (float*)(ws + 33737728); // [3][16] LN partials
  int*   flag  = (int*)(ws + 33737920);

  size_t coff = 33740800;
  auto alloc = [&](size_t elems) -> u16* {
    u16* p = (u16*)(ws + coff);
    coff += ((elems*2 + 255)/256)*256;
    return p;
  };
  u16* dyb   = alloc(33554432);
  u16* dytb  = alloc(33554432);
  u16* stgb  = alloc(4194304);
  u16* encWf = alloc(98304);
  u16* encbf = alloc(768);
  u16* encWg = alloc(98304);
  u16* encbg = alloc(768);
  u16* skW   = alloc(98304);
  u16* skb   = alloc(768);
  u16* nw    = alloc(196608);
  u16* nb    = alloc(196608);
  u16* g0W   = alloc(9216);
  u16* g0b   = alloc(96);
  u16* g1W   = alloc(9216);
  u16* g1b   = alloc(96);
  u16* g2W   = alloc(9216);
  u16* g2b   = alloc(96);
  u16* sEW   = alloc(8192);
  u16* sEb   = alloc(256);
  u16* eW    = alloc(3072);
  u16* eb    = alloc(12);

  hipLaunchKernelGGL(kdetect, dim3(1), dim3(256), 0, stream, (const u16*)d_in[0], flag);

  CvtTab tb;
  {
    const void* ss[18] = { d_in[6], d_in[7], d_in[8], d_in[9], d_in[10], d_in[11],
      d_in[12], d_in[13], d_in[14], d_in[15], d_in[16], d_in[17], d_in[18], d_in[19],
      d_in[20], d_in[21], d_in[22], d_in[23] };
    u16* dd[18] = { encWf, encbf, encWg, encbg, skW, skb, nw, nb,
      g0W, g0b, g1W, g1b, g2W, g2b, sEW, sEb, eW, eb };
    const int nn[18] = { 24576, 192, 24576, 192, 24576, 192, 49152, 49152,
      2304, 24, 2304, 24, 2304, 24, 2048, 64, 768, 3 };
    for (int e = 0; e < 18; e++) { tb.s[e] = ss[e]; tb.d[e] = dd[e]; tb.n4[e] = nn[e]; }
  }
  hipLaunchKernelGGL(kcvt_small, dim3(192, 18), dim3(256), 0, stream, tb, flag);
  hipLaunchKernelGGL(kweff3, dim3(28, 3), dim3(256), 0, stream,
      g0W, g1W, g2W, g0b, g1b, g2b, weff, bw);
  hipLaunchKernelGGL(kstg, dim3(512), dim3(256), 0, stream, d_in[2], stgb, rst, flag);
  hipMemsetAsync(rdy, 0, 131264, stream);   // rdy + cdy + raw
  hipLaunchKernelGGL(kcvtT, dim3(8,32,8), dim3(256), 0, stream,
      d_in[1], dyb, dytb, rdy, cdy, flag);
  hipLaunchKernelGGL(khid0, dim3(32,8), dim3(256), 0, stream,
      d_in[0], d_in[3], d_in[4], d_in[5], hid, pbuf, flag);

  for (int i = 0; i < 3; i++) {
    hipLaunchKernelGGL(ktcnfuse, dim3(256), dim3(256), 0, stream,
        hid,
        encWf + (i*2+0)*16384, encbf + (i*2+0)*128, encWg + (i*2+0)*16384, encbg + (i*2+0)*128,
        encWf + (i*2+1)*16384, encbf + (i*2+1)*128, encWg + (i*2+1)*16384, encbg + (i*2+1)*128,
        skW + i*32768, skb + i*256, skip, (i>0)?1:0);

    // hop 1: shared X (= x). pbuf slots 1..3 + pbufT cols 0/64/128.
    P3 p1;
    p1.A0 = stgb; p1.A1 = dyb; p1.A2 = dytb;
    p1.ab0 = 0;   p1.ab1 = DYB; p1.ab2 = DYB;
    p1.X0 = pbuf; p1.X1 = pbuf; p1.X2 = pbuf;
    p1.R0 = rst;  p1.R1 = rdy;  p1.R2 = cdy;
    p1.rb0 = 0;   p1.rb1 = 2048; p1.rb2 = 2048;
    p1.O0 = pbuf + 1*SL; p1.O1 = pbuf + 2*SL; p1.O2 = pbuf + 3*SL;
    p1.T0 = pbufT + 0;   p1.T1 = pbufT + 64;  p1.T2 = pbufT + 128;
    hipLaunchKernelGGL((kprop3<1,1>), dim3(128,8), dim3(256), 0, stream, p1, PB, PB);

    // hop 2: per-graph X (= p1 slots). pbufT cols 32/96/160 only.
    P3 p2 = p1;
    p2.X0 = pbuf + 1*SL; p2.X1 = pbuf + 2*SL; p2.X2 = pbuf + 3*SL;
    p2.T0 = pbufT + 32;  p2.T1 = pbufT + 96;  p2.T2 = pbufT + 160;
    hipLaunchKernelGGL((kprop3<0,0>), dim3(128,8), dim3(256), 0, stream, p2, PB, PB);

    hipLaunchKernelGGL(kcomb, dim3(256), dim3(256), 0, stream,
        hid, pbufT, pbuf, weff + i*7168, bw + i*32, xpre, raw + i*16);
    hipLaunchKernelGGL(kapply, dim3(32,8), dim3(256), 0, stream,
        xpre, raw + i*16, nw + i*65536, nb + i*65536, pbuf, hid);
  }
  hipLaunchKernelGGL(kfinal, dim3(256), dim3(256), 0, stream,
      hid, sEW, sEb, skip, eW, eb, d_out, flag);
}